// Round 1
// baseline (1631.308 us; speedup 1.0000x reference)
//
#include <hip/hip_runtime.h>
#include <hip/hip_bf16.h>

#define B_ 2048
#define L_ 200
#define D_ 256
#define K_ 8
#define TILE_L 32

// ------------------------------------------------------------------
// Kernel 1: u_hat[m,e] = sum_d X[m,d] * W[e,d]
// M = B*L = 409600, N = 256, Kdim = 256.  BM=BN=128, BK=16, 256 thr, 8x8/thr.
// ------------------------------------------------------------------
__global__ __launch_bounds__(256) void uhat_gemm(const float* __restrict__ X,
                                                 const float* __restrict__ W,
                                                 float* __restrict__ U) {
    __shared__ float As[16][132];   // k-major, padded (+4) for bank spread
    __shared__ float Bs[16][132];

    const int bn = blockIdx.x;          // 0..1
    const int bm = blockIdx.y;          // 0..3199
    const int t  = threadIdx.x;
    const int tx = t & 15;
    const int ty = t >> 4;
    const int m0 = bm * 128;
    const int e0 = bn * 128;

    float acc[8][8];
#pragma unroll
    for (int i = 0; i < 8; ++i)
#pragma unroll
        for (int j = 0; j < 8; ++j) acc[i][j] = 0.f;

    const int lr = t >> 2;              // 0..63
    const int lc = (t & 3) << 2;        // 0,4,8,12

    for (int k0 = 0; k0 < 256; k0 += 16) {
#pragma unroll
        for (int j = 0; j < 2; ++j) {
            const int row = lr + 64 * j;
            const float4 v = *(const float4*)(X + (size_t)(m0 + row) * 256 + k0 + lc);
            As[lc + 0][row] = v.x;
            As[lc + 1][row] = v.y;
            As[lc + 2][row] = v.z;
            As[lc + 3][row] = v.w;
            const float4 w = *(const float4*)(W + (size_t)(e0 + row) * 256 + k0 + lc);
            Bs[lc + 0][row] = w.x;
            Bs[lc + 1][row] = w.y;
            Bs[lc + 2][row] = w.z;
            Bs[lc + 3][row] = w.w;
        }
        __syncthreads();
#pragma unroll
        for (int kk = 0; kk < 16; ++kk) {
            float a[8], b[8];
#pragma unroll
            for (int i = 0; i < 8; ++i) a[i] = As[kk][ty * 8 + i];
#pragma unroll
            for (int j = 0; j < 8; ++j) b[j] = Bs[kk][tx * 8 + j];
#pragma unroll
            for (int i = 0; i < 8; ++i)
#pragma unroll
                for (int j = 0; j < 8; ++j)
                    acc[i][j] = fmaf(a[i], b[j], acc[i][j]);
        }
        __syncthreads();
    }
#pragma unroll
    for (int i = 0; i < 8; ++i) {
        float4 v0 = make_float4(acc[i][0], acc[i][1], acc[i][2], acc[i][3]);
        float4 v1 = make_float4(acc[i][4], acc[i][5], acc[i][6], acc[i][7]);
        float* p = U + (size_t)(m0 + ty * 8 + i) * 256 + e0 + tx * 8;
        *(float4*)p       = v0;
        *(float4*)(p + 4) = v1;
    }
}

// ------------------------------------------------------------------
// Kernel 2: dynamic routing, one block (256 thr) per batch.
// ------------------------------------------------------------------
__global__ __launch_bounds__(256) void routing(const float* __restrict__ U,
                                               const float* __restrict__ b_init,
                                               const int* __restrict__ mask,
                                               float* __restrict__ out) {
    __shared__ float lb[K_][L_];        // routing logits
    __shared__ float lwT[L_][K_];       // softmax weights (transposed)
    __shared__ float lc[K_][260];       // squash output c (padded)
    __shared__ float ut[TILE_L][260];   // staged u_hat tile (padded)
    __shared__ float red[4][K_];        // cross-wave reduce scratch

    const int b = blockIdx.x;
    const int t = threadIdx.x;
    const int d = t;                    // 0..255 == D
    const float* Ub = U + (size_t)b * L_ * D_;

    // init logits with mask
    for (int idx = t; idx < K_ * L_; idx += 256) {
        const int k = idx / L_, l = idx % L_;
        lb[k][l] = (mask[b * L_ + l] == 0) ? -1e9f
                                           : b_init[((size_t)b * K_ + k) * L_ + l];
    }
    __syncthreads();

    const int wv   = t >> 6;            // wave 0..3
    const int grp  = t >> 5;            // k row for softmax (0..7)
    const int lane = t & 31;

    for (int iter = 0; iter < 3; ++iter) {
        // ---- softmax over l for row k = grp (32 threads per row) ----
        {
            const int k = grp;
            float ev[7];
            float m = -1e30f;
#pragma unroll
            for (int i = 0; i < 7; ++i) {
                const int l = lane + 32 * i;
                if (l < L_) m = fmaxf(m, lb[k][l]);
            }
#pragma unroll
            for (int off = 16; off >= 1; off >>= 1)
                m = fmaxf(m, __shfl_xor(m, off));
            float s = 0.f;
#pragma unroll
            for (int i = 0; i < 7; ++i) {
                const int l = lane + 32 * i;
                float e = 0.f;
                if (l < L_) { e = __expf(lb[k][l] - m); s += e; }
                ev[i] = e;
            }
#pragma unroll
            for (int off = 16; off >= 1; off >>= 1)
                s += __shfl_xor(s, off);
            const float rinv = 1.0f / s;
#pragma unroll
            for (int i = 0; i < 7; ++i) {
                const int l = lane + 32 * i;
                if (l < L_) lwT[l][k] = ev[i] * rinv;
            }
        }
        __syncthreads();

        // ---- z pass: thread owns output column d; stream u_hat rows ----
        float z[K_];
#pragma unroll
        for (int k = 0; k < K_; ++k) z[k] = 0.f;
#pragma unroll 4
        for (int l = 0; l < L_; ++l) {
            const float u = Ub[l * D_ + d];
            const float4 w0 = *(const float4*)&lwT[l][0];
            const float4 w1 = *(const float4*)&lwT[l][4];
            z[0] = fmaf(w0.x, u, z[0]);
            z[1] = fmaf(w0.y, u, z[1]);
            z[2] = fmaf(w0.z, u, z[2]);
            z[3] = fmaf(w0.w, u, z[3]);
            z[4] = fmaf(w1.x, u, z[4]);
            z[5] = fmaf(w1.y, u, z[5]);
            z[6] = fmaf(w1.z, u, z[6]);
            z[7] = fmaf(w1.w, u, z[7]);
        }

        // ---- norms: ns[k] = sum_d z[k][d]^2 (block reduce) ----
#pragma unroll
        for (int k = 0; k < K_; ++k) {
            float v = z[k] * z[k];
#pragma unroll
            for (int off = 32; off >= 1; off >>= 1)
                v += __shfl_xor(v, off);
            if ((t & 63) == 0) red[wv][k] = v;
        }
        __syncthreads();
        float scale[K_];
#pragma unroll
        for (int k = 0; k < K_; ++k) {
            const float ns = red[0][k] + red[1][k] + red[2][k] + red[3][k];
            scale[k] = ns / ((1.f + ns) * sqrtf(ns + 1e-8f));
        }

        if (iter == 2) {
            float* op = out + (size_t)b * K_ * D_ + d;
#pragma unroll
            for (int k = 0; k < K_; ++k) op[k * D_] = scale[k] * z[k];
        } else {
            // c into LDS for the b-update
#pragma unroll
            for (int k = 0; k < K_; ++k) lc[k][d] = scale[k] * z[k];
            __syncthreads();

            // ---- b-update: lb[k][l] += sum_d c[k][d] * u_hat[l][d] ----
            const int lk = t & 7;       // k
            const int ll = t >> 3;      // local l (0..31)
            const int scol  = (t & 63) << 2;
            const int srow0 = t >> 6;
            for (int l0 = 0; l0 < L_; l0 += TILE_L) {
                const int rows = (L_ - l0 < TILE_L) ? (L_ - l0) : TILE_L;
                for (int j = 0; j < (rows >> 2); ++j) {
                    const int r = srow0 + 4 * j;
                    *(float4*)&ut[r][scol] =
                        *(const float4*)(Ub + (size_t)(l0 + r) * D_ + scol);
                }
                __syncthreads();
                if (ll < rows) {
                    float sum = 0.f;
#pragma unroll 8
                    for (int d4 = 0; d4 < 64; ++d4) {
                        const float4 cv = *(const float4*)&lc[lk][d4 * 4];
                        const float4 uv = *(const float4*)&ut[ll][d4 * 4];
                        sum += cv.x * uv.x + cv.y * uv.y + cv.z * uv.z + cv.w * uv.w;
                    }
                    lb[lk][l0 + ll] += sum;
                }
                __syncthreads();
            }
        }
    }
}

// ------------------------------------------------------------------
extern "C" void kernel_launch(void* const* d_in, const int* in_sizes, int n_in,
                              void* d_out, int out_size, void* d_ws, size_t ws_size,
                              hipStream_t stream) {
    (void)in_sizes; (void)n_in; (void)out_size; (void)ws_size;
    const float* behavior = (const float*)d_in[0];   // [B, L, D]
    const float* W        = (const float*)d_in[1];   // [D, D]
    const float* b_init   = (const float*)d_in[2];   // [B, K, L]
    const int*   mask     = (const int*)d_in[3];     // [B, L]
    float* out  = (float*)d_out;                     // [B, K, D]
    float* uhat = (float*)d_ws;                      // [B, L, D] scratch

    dim3 ggrid(2, 3200);
    uhat_gemm<<<ggrid, 256, 0, stream>>>(behavior, W, uhat);
    routing<<<2048, 256, 0, stream>>>(uhat, b_init, mask, out);
}

// Round 2
// 757.847 us; speedup vs baseline: 2.1526x; 2.1526x over previous
//
#include <hip/hip_runtime.h>
#include <hip/hip_bf16.h>

#define B_ 2048
#define L_ 200
#define D_ 256
#define K_ 8

typedef __attribute__((ext_vector_type(8))) _Float16 half8;
typedef __attribute__((ext_vector_type(2))) _Float16 half2v;
typedef __attribute__((ext_vector_type(4))) float f32x4;

// ==================================================================
// Kernel 1: u_hat[m,e] = sum_d X[m,d] * W[e,d], fp16 MFMA, out fp16.
// M = 409600, N = 256, K = 256. 128x128 tile, BK=32, 256 thr (4 waves,
// each wave a 64x64 quadrant, 4x4 frags of 16x16x32).
// ==================================================================
#define APAD 40   // fp16 elems per LDS row (32 data + 8 pad)
#define CPAD 136  // fp16 elems per C-tile LDS row

__global__ __launch_bounds__(256) void uhat_gemm_f16(const float* __restrict__ X,
                                                     const float* __restrict__ W,
                                                     _Float16* __restrict__ U) {
    __shared__ _Float16 smem[128 * CPAD];   // 34816 B; staging A/B carved below
    _Float16* As = smem;                    // [128][APAD]
    _Float16* Bs = smem + 128 * APAD;       // [128][APAD]

    const int bn = blockIdx.x;              // 0..1
    const int bm = blockIdx.y;              // 0..3199
    const int t  = threadIdx.x;
    const int wave = t >> 6;
    const int lane = t & 63;
    const int m0 = bm * 128, e0 = bn * 128;
    const int wm = (wave >> 1) * 64, wn = (wave & 1) * 64;
    const int fr = lane & 15;               // frag row/col index
    const int fk = (lane >> 4) * 8;         // frag k offset

    f32x4 acc[4][4] = {};

    const int sr = t >> 1;                  // staging row 0..127
    const int sc = (t & 1) * 16;            // staging col 0 or 16

    for (int k0 = 0; k0 < 256; k0 += 32) {
        // ---- stage A (X) and B (W) tiles, fp32 -> fp16 ----
        const float* xp = X + (size_t)(m0 + sr) * 256 + k0 + sc;
        const float* wp = W + (size_t)(e0 + sr) * 256 + k0 + sc;
        float xv[16], wv[16];
#pragma unroll
        for (int i = 0; i < 4; ++i) {
            *(float4*)&xv[4 * i] = *(const float4*)(xp + 4 * i);
            *(float4*)&wv[4 * i] = *(const float4*)(wp + 4 * i);
        }
        _Float16 xh[16], wh[16];
#pragma unroll
        for (int i = 0; i < 16; ++i) { xh[i] = (_Float16)xv[i]; wh[i] = (_Float16)wv[i]; }
        *(half8*)&As[sr * APAD + sc]     = *(half8*)&xh[0];
        *(half8*)&As[sr * APAD + sc + 8] = *(half8*)&xh[8];
        *(half8*)&Bs[sr * APAD + sc]     = *(half8*)&wh[0];
        *(half8*)&Bs[sr * APAD + sc + 8] = *(half8*)&wh[8];
        __syncthreads();

        // ---- fragments + MFMA ----
        half8 af[4], bf[4];
#pragma unroll
        for (int mi = 0; mi < 4; ++mi)
            af[mi] = *(const half8*)&As[(wm + mi * 16 + fr) * APAD + fk];
#pragma unroll
        for (int ni = 0; ni < 4; ++ni)
            bf[ni] = *(const half8*)&Bs[(wn + ni * 16 + fr) * APAD + fk];
#pragma unroll
        for (int mi = 0; mi < 4; ++mi)
#pragma unroll
            for (int ni = 0; ni < 4; ++ni)
                acc[mi][ni] = __builtin_amdgcn_mfma_f32_16x16x32_f16(
                    af[mi], bf[ni], acc[mi][ni], 0, 0, 0);
        __syncthreads();
    }

    // ---- epilogue: acc -> LDS fp16 tile -> coalesced store ----
    const int crow = (lane >> 4) * 4;
#pragma unroll
    for (int mi = 0; mi < 4; ++mi)
#pragma unroll
        for (int ni = 0; ni < 4; ++ni)
#pragma unroll
            for (int j = 0; j < 4; ++j)
                smem[(wm + mi * 16 + crow + j) * CPAD + wn + ni * 16 + fr] =
                    (_Float16)acc[mi][ni][j];
    __syncthreads();

    const int orow = t >> 1;
    const int ocol = (t & 1) * 64;
#pragma unroll
    for (int i = 0; i < 8; ++i)
        *(half8*)(U + (size_t)(m0 + orow) * 256 + e0 + ocol + 8 * i) =
            *(const half8*)&smem[orow * CPAD + ocol + 8 * i];
}

// ==================================================================
// Kernel 2: dynamic routing, one block (256 thr) per batch,
// u_hat LDS-resident in fp16 (loaded once from HBM).
// ==================================================================
#define UTPAD 264   // fp16 elems per ut row (256 + 8 pad -> conflict-free)

__global__ __launch_bounds__(256) void routing_f16(const _Float16* __restrict__ U,
                                                   const float* __restrict__ b_init,
                                                   const int* __restrict__ mask,
                                                   float* __restrict__ out) {
    extern __shared__ char dyn[];
    _Float16* ut = (_Float16*)dyn;                       // [200][UTPAD] 105600 B
    float* lb    = (float*)(dyn + 105600);               // [8][200]     6400 B
    float* lwT   = (float*)(dyn + 105600 + 6400);        // [200][8]     6400 B
    float* lc    = (float*)(dyn + 105600 + 12800);       // [8][UTPAD]   8448 B
    float* red   = (float*)(dyn + 105600 + 12800 + 8448);// [4][8]       128 B

    const int b = blockIdx.x;
    const int t = threadIdx.x;
    const int d = t;                                     // 0..255
    const _Float16* Ub = U + (size_t)b * L_ * D_;

    // ---- load u_hat into LDS (once) ----
#pragma unroll
    for (int i = 0; i < 25; ++i) {
        const int r = (t >> 5) + 8 * i;                  // 0..199
        const int c = (t & 31) * 8;                      // 0..248
        *(half8*)&ut[r * UTPAD + c] = *(const half8*)(Ub + r * 256 + c);
    }
    // ---- init logits with mask ----
    for (int idx = t; idx < K_ * L_; idx += 256) {
        const int k = idx / L_, l = idx % L_;
        lb[k * L_ + l] = (mask[b * L_ + l] == 0)
                             ? -1e9f
                             : b_init[((size_t)b * K_ + k) * L_ + l];
    }
    __syncthreads();

    const int wv   = t >> 6;
    const int grp  = t >> 5;
    const int lane = t & 31;

    for (int iter = 0; iter < 3; ++iter) {
        // ---- softmax over l for row k = grp (32 threads per row) ----
        {
            const int k = grp;
            float ev[7];
            float m = -1e30f;
#pragma unroll
            for (int i = 0; i < 7; ++i) {
                const int l = lane + 32 * i;
                if (l < L_) m = fmaxf(m, lb[k * L_ + l]);
            }
#pragma unroll
            for (int off = 16; off >= 1; off >>= 1)
                m = fmaxf(m, __shfl_xor(m, off));
            float s = 0.f;
#pragma unroll
            for (int i = 0; i < 7; ++i) {
                const int l = lane + 32 * i;
                float e = 0.f;
                if (l < L_) { e = __expf(lb[k * L_ + l] - m); s += e; }
                ev[i] = e;
            }
#pragma unroll
            for (int off = 16; off >= 1; off >>= 1)
                s += __shfl_xor(s, off);
            const float rinv = 1.0f / s;
#pragma unroll
            for (int i = 0; i < 7; ++i) {
                const int l = lane + 32 * i;
                if (l < L_) lwT[l * K_ + k] = ev[i] * rinv;
            }
        }
        __syncthreads();

        // ---- z pass: thread owns column d; all u_hat reads from LDS ----
        float z[K_];
#pragma unroll
        for (int k = 0; k < K_; ++k) z[k] = 0.f;
#pragma unroll 4
        for (int l = 0; l < L_; ++l) {
            const float u = (float)ut[l * UTPAD + d];
            const float4 w0 = *(const float4*)&lwT[l * K_];
            const float4 w1 = *(const float4*)&lwT[l * K_ + 4];
            z[0] = fmaf(w0.x, u, z[0]);
            z[1] = fmaf(w0.y, u, z[1]);
            z[2] = fmaf(w0.z, u, z[2]);
            z[3] = fmaf(w0.w, u, z[3]);
            z[4] = fmaf(w1.x, u, z[4]);
            z[5] = fmaf(w1.y, u, z[5]);
            z[6] = fmaf(w1.z, u, z[6]);
            z[7] = fmaf(w1.w, u, z[7]);
        }

        // ---- norms ----
#pragma unroll
        for (int k = 0; k < K_; ++k) {
            float v = z[k] * z[k];
#pragma unroll
            for (int off = 32; off >= 1; off >>= 1)
                v += __shfl_xor(v, off);
            if ((t & 63) == 0) red[wv * K_ + k] = v;
        }
        __syncthreads();
        float scale[K_];
#pragma unroll
        for (int k = 0; k < K_; ++k) {
            const float ns = red[0 * K_ + k] + red[1 * K_ + k] +
                             red[2 * K_ + k] + red[3 * K_ + k];
            scale[k] = ns / ((1.f + ns) * sqrtf(ns + 1e-8f));
        }

        if (iter == 2) {
            float* op = out + (size_t)b * K_ * D_ + d;
#pragma unroll
            for (int k = 0; k < K_; ++k) op[k * D_] = scale[k] * z[k];
        } else {
#pragma unroll
            for (int k = 0; k < K_; ++k) lc[k * UTPAD + d] = scale[k] * z[k];
            __syncthreads();

            // ---- b-update: lb[k][l] += sum_d c[k][d] * u_hat[l][d] ----
            const int lk = t & 7;
            const int lrow = t >> 3;                     // 0..31
            for (int l0 = 0; l0 < L_; l0 += 32) {
                const int l = l0 + lrow;
                if (l < L_) {
                    float sum = 0.f;
#pragma unroll 16
                    for (int d2 = 0; d2 < 128; ++d2) {
                        const half2v u2 = *(const half2v*)&ut[l * UTPAD + 2 * d2];
                        const float2 cv = *(const float2*)&lc[lk * UTPAD + 2 * d2];
                        sum = fmaf((float)u2[0], cv.x, sum);
                        sum = fmaf((float)u2[1], cv.y, sum);
                    }
                    lb[lk * L_ + l] += sum;
                }
            }
            __syncthreads();
        }
    }
}

// ==================================================================
extern "C" void kernel_launch(void* const* d_in, const int* in_sizes, int n_in,
                              void* d_out, int out_size, void* d_ws, size_t ws_size,
                              hipStream_t stream) {
    (void)in_sizes; (void)n_in; (void)out_size; (void)ws_size;
    const float* behavior = (const float*)d_in[0];   // [B, L, D]
    const float* W        = (const float*)d_in[1];   // [D, D]
    const float* b_init   = (const float*)d_in[2];   // [B, K, L]
    const int*   mask     = (const int*)d_in[3];     // [B, L]
    float* out      = (float*)d_out;                 // [B, K, D]
    _Float16* uhat  = (_Float16*)d_ws;               // [B, L, D] fp16 scratch

    const int routing_lds = 105600 + 6400 + 6400 + 8448 + 128;  // 126976 B
    static bool attr_set = false;
    hipFuncSetAttribute((const void*)routing_f16,
                        hipFuncAttributeMaxDynamicSharedMemorySize, routing_lds);

    dim3 ggrid(2, 3200);
    uhat_gemm_f16<<<ggrid, 256, 0, stream>>>(behavior, W, uhat);
    routing_f16<<<2048, 256, routing_lds, stream>>>(uhat, b_init, mask, out);
}

// Round 4
// 407.144 us; speedup vs baseline: 4.0067x; 1.8614x over previous
//
#include <hip/hip_runtime.h>
#include <hip/hip_bf16.h>

#define B_ 2048
#define L_ 200
#define D_ 256
#define K_ 8
#define UTP 264     // fp16 stride for ut rows (528B, 16B-aligned)
#define CHP 264     // fp16 stride for cH/cL rows

typedef __attribute__((ext_vector_type(8))) _Float16 half8;
typedef __attribute__((ext_vector_type(2))) _Float16 half2v;
typedef __attribute__((ext_vector_type(4))) float f32x4;

// ==================================================================
// Kernel 1: u_hat = X @ W^T, fp16 MFMA, out fp16.  (verified, unchanged)
// ==================================================================
#define APAD 40
#define CPAD 136

__global__ __launch_bounds__(256) void uhat_gemm_f16(const float* __restrict__ X,
                                                     const float* __restrict__ W,
                                                     _Float16* __restrict__ U) {
    __shared__ _Float16 smem[128 * CPAD];
    _Float16* As = smem;
    _Float16* Bs = smem + 128 * APAD;

    const int bn = blockIdx.x;
    const int bm = blockIdx.y;
    const int t  = threadIdx.x;
    const int wave = t >> 6;
    const int lane = t & 63;
    const int m0 = bm * 128, e0 = bn * 128;
    const int wm = (wave >> 1) * 64, wn = (wave & 1) * 64;
    const int fr = lane & 15;
    const int fk = (lane >> 4) * 8;

    f32x4 acc[4][4] = {};

    const int sr = t >> 1;
    const int sc = (t & 1) * 16;

    for (int k0 = 0; k0 < 256; k0 += 32) {
        const float* xp = X + (size_t)(m0 + sr) * 256 + k0 + sc;
        const float* wp = W + (size_t)(e0 + sr) * 256 + k0 + sc;
        float xv[16], wv[16];
#pragma unroll
        for (int i = 0; i < 4; ++i) {
            *(float4*)&xv[4 * i] = *(const float4*)(xp + 4 * i);
            *(float4*)&wv[4 * i] = *(const float4*)(wp + 4 * i);
        }
        _Float16 xh[16], wh[16];
#pragma unroll
        for (int i = 0; i < 16; ++i) { xh[i] = (_Float16)xv[i]; wh[i] = (_Float16)wv[i]; }
        *(half8*)&As[sr * APAD + sc]     = *(half8*)&xh[0];
        *(half8*)&As[sr * APAD + sc + 8] = *(half8*)&xh[8];
        *(half8*)&Bs[sr * APAD + sc]     = *(half8*)&wh[0];
        *(half8*)&Bs[sr * APAD + sc + 8] = *(half8*)&wh[8];
        __syncthreads();

        half8 af[4], bf[4];
#pragma unroll
        for (int mi = 0; mi < 4; ++mi)
            af[mi] = *(const half8*)&As[(wm + mi * 16 + fr) * APAD + fk];
#pragma unroll
        for (int ni = 0; ni < 4; ++ni)
            bf[ni] = *(const half8*)&Bs[(wn + ni * 16 + fr) * APAD + fk];
#pragma unroll
        for (int mi = 0; mi < 4; ++mi)
#pragma unroll
            for (int ni = 0; ni < 4; ++ni)
                acc[mi][ni] = __builtin_amdgcn_mfma_f32_16x16x32_f16(
                    af[mi], bf[ni], acc[mi][ni], 0, 0, 0);
        __syncthreads();
    }

    const int crow = (lane >> 4) * 4;
#pragma unroll
    for (int mi = 0; mi < 4; ++mi)
#pragma unroll
        for (int ni = 0; ni < 4; ++ni)
#pragma unroll
            for (int j = 0; j < 4; ++j)
                smem[(wm + mi * 16 + crow + j) * CPAD + wn + ni * 16 + fr] =
                    (_Float16)acc[mi][ni][j];
    __syncthreads();

    const int orow = t >> 1;
    const int ocol = (t & 1) * 64;
#pragma unroll
    for (int i = 0; i < 8; ++i)
        *(half8*)(U + (size_t)(m0 + orow) * 256 + e0 + ocol + 8 * i) =
            *(const half8*)&smem[orow * CPAD + ocol + 8 * i];
}

// ==================================================================
// Kernel 2: routing, 1024 threads (16 waves) per batch.
//   LDS layout (bytes):
//     ut  [200][264] f16          @ 0       (105600)
//     zp  [4][8][256] f32         @ 105600  (32768)   -- overlaid with:
//       cH [16][264] f16          @ 105600  (8448)
//       cL [16][264] f16          @ 114048  (8448)
//     lb  [8][200] f32            @ 138368  (6400)
//     wS  [200][8] f32            @ 144768  (6400)
//     red [16] f32                @ 151168  (64)
// ==================================================================
#define OFF_ZP  105600
#define OFF_LB  (OFF_ZP + 32768)
#define OFF_WS  (OFF_LB + 6400)
#define OFF_RED (OFF_WS + 6400)
#define LDS_TOTAL (OFF_RED + 64)   // 151232 B

__global__ __launch_bounds__(1024) void routing3(const _Float16* __restrict__ U,
                                                 const float* __restrict__ b_init,
                                                 const int* __restrict__ mask,
                                                 float* __restrict__ out) {
    extern __shared__ char dyn[];
    _Float16* ut = (_Float16*)dyn;
    float*    zp = (float*)(dyn + OFF_ZP);
    _Float16* cH = (_Float16*)(dyn + OFF_ZP);            // overlay (time-disjoint)
    _Float16* cL = (_Float16*)(dyn + OFF_ZP + 8448);     // overlay
    float*    lb = (float*)(dyn + OFF_LB);
    float*    wS = (float*)(dyn + OFF_WS);
    float*    red = (float*)(dyn + OFF_RED);

    const int b = blockIdx.x;
    const int t = threadIdx.x;
    const _Float16* Ub = U + (size_t)b * L_ * D_;

    // ---- load u_hat into LDS (once) ----
#pragma unroll
    for (int i = 0; i < 7; ++i) {
        const int idx = t + 1024 * i;
        if (idx < 6400) {
            const int r = idx >> 5, c = (idx & 31) * 8;
            *(half8*)&ut[r * UTP + c] = *(const half8*)(Ub + r * 256 + c);
        }
    }
    // ---- init logits with mask ----
    for (int idx = t; idx < K_ * L_; idx += 1024) {
        const int k = idx / L_, l = idx % L_;
        lb[k * L_ + l] = (mask[b * L_ + l] == 0)
                             ? -1e9f
                             : b_init[((size_t)b * K_ + k) * L_ + l];
    }
    __syncthreads();

    for (int iter = 0; iter < 3; ++iter) {
        // ---- softmax: waves 0..7, wave k over L (fp32 weights) ----
        if (t < 512) {
            const int k = t >> 6, lane = t & 63;
            float v[4];
            float m = -1e30f;
#pragma unroll
            for (int i = 0; i < 4; ++i) {
                const int l = lane + 64 * i;
                v[i] = (l < L_) ? lb[k * L_ + l] : -1e30f;
                m = fmaxf(m, v[i]);
            }
#pragma unroll
            for (int off = 32; off >= 1; off >>= 1)
                m = fmaxf(m, __shfl_xor(m, off));
            float e[4], s = 0.f;
#pragma unroll
            for (int i = 0; i < 4; ++i) {
                const int l = lane + 64 * i;
                e[i] = (l < L_) ? __expf(v[i] - m) : 0.f;
                s += e[i];
            }
#pragma unroll
            for (int off = 32; off >= 1; off >>= 1)
                s += __shfl_xor(s, off);
            const float rinv = 1.0f / s;
#pragma unroll
            for (int i = 0; i < 4; ++i) {
                const int l = lane + 64 * i;
                if (l < L_) wS[l * 8 + k] = e[i] * rinv;
            }
        }
        __syncthreads();

        // ---- z-pass: 512 threads, thread (q,c2) owns d=2c2..2c2+1, 50 l's ----
        if (t < 512) {
            const int q = t >> 7, c2 = t & 127;
            float z0[8] = {}, z1[8] = {};
            const int lend = 50 * q + 50;
#pragma unroll 2
            for (int l = 50 * q; l < lend; ++l) {
                const half2v u2 = *(const half2v*)&ut[l * UTP + 2 * c2];
                const float4 w0 = *(const float4*)&wS[l * 8];
                const float4 w1 = *(const float4*)&wS[l * 8 + 4];
                const float u0 = (float)u2[0], u1 = (float)u2[1];
                z0[0] = fmaf(w0.x, u0, z0[0]);  z1[0] = fmaf(w0.x, u1, z1[0]);
                z0[1] = fmaf(w0.y, u0, z0[1]);  z1[1] = fmaf(w0.y, u1, z1[1]);
                z0[2] = fmaf(w0.z, u0, z0[2]);  z1[2] = fmaf(w0.z, u1, z1[2]);
                z0[3] = fmaf(w0.w, u0, z0[3]);  z1[3] = fmaf(w0.w, u1, z1[3]);
                z0[4] = fmaf(w1.x, u0, z0[4]);  z1[4] = fmaf(w1.x, u1, z1[4]);
                z0[5] = fmaf(w1.y, u0, z0[5]);  z1[5] = fmaf(w1.y, u1, z1[5]);
                z0[6] = fmaf(w1.z, u0, z0[6]);  z1[6] = fmaf(w1.z, u1, z1[6]);
                z0[7] = fmaf(w1.w, u0, z0[7]);  z1[7] = fmaf(w1.w, u1, z1[7]);
            }
#pragma unroll
            for (int k = 0; k < 8; ++k)
                *(float2*)&zp[(q * 8 + k) * 256 + 2 * c2] = make_float2(z0[k], z1[k]);
        }
        __syncthreads();

        // ---- reduce partials -> squash scale (all 1024 threads) ----
        {
            const int k = t >> 7, dd = t & 127;
            float zs0 = 0.f, zs1 = 0.f;
#pragma unroll
            for (int q = 0; q < 4; ++q) {
                zs0 += zp[(q * 8 + k) * 256 + dd];
                zs1 += zp[(q * 8 + k) * 256 + dd + 128];
            }
            float sq = zs0 * zs0 + zs1 * zs1;
#pragma unroll
            for (int off = 32; off >= 1; off >>= 1)
                sq += __shfl_xor(sq, off);
            if ((t & 63) == 0) red[t >> 6] = sq;
            __syncthreads();   // red ready AND all zp reads drained (overlay safe)
            const float ns = red[2 * k] + red[2 * k + 1];
            const float scale = ns / ((1.f + ns) * sqrtf(ns + 1e-8f));

            if (iter == 2) {
                float* op = out + (size_t)b * K_ * D_ + k * 256 + dd;
                op[0]   = scale * zs0;
                op[128] = scale * zs1;
            } else {
                const float v0 = scale * zs0, v1 = scale * zs1;
                const _Float16 h0 = (_Float16)v0, h1 = (_Float16)v1;
                cH[k * CHP + dd]       = h0;
                cH[k * CHP + dd + 128] = h1;
                cL[k * CHP + dd]       = (_Float16)(v0 - (float)h0);
                cL[k * CHP + dd + 128] = (_Float16)(v1 - (float)h1);
            }
        }
        if (iter == 2) break;
        __syncthreads();

        // ---- b-update via MFMA: lb[k][l] += sum_d u[l,d]*(cH+cL)[k,d] ----
        {
            const int w = t >> 6, lane = t & 63;
            if (w < 13) {
                const int l0 = 16 * w;
                const int ar = (l0 + (lane & 15)) * UTP;
                const int br = (lane & 15) * CHP;
                const int koff = (lane >> 4) * 8;
                f32x4 acc = {};
#pragma unroll
                for (int d0 = 0; d0 < 256; d0 += 32) {
                    const half8 a8 = *(const half8*)&ut[ar + d0 + koff];
                    acc = __builtin_amdgcn_mfma_f32_16x16x32_f16(
                        a8, *(const half8*)&cH[br + d0 + koff], acc, 0, 0, 0);
                    acc = __builtin_amdgcn_mfma_f32_16x16x32_f16(
                        a8, *(const half8*)&cL[br + d0 + koff], acc, 0, 0, 0);
                }
                const int kcol = lane & 15;
                if (kcol < 8) {
#pragma unroll
                    for (int j = 0; j < 4; ++j) {
                        const int l = l0 + (lane >> 4) * 4 + j;
                        if (l < L_) lb[kcol * L_ + l] += acc[j];
                    }
                }
            }
        }
        __syncthreads();
    }
}

// ==================================================================
extern "C" void kernel_launch(void* const* d_in, const int* in_sizes, int n_in,
                              void* d_out, int out_size, void* d_ws, size_t ws_size,
                              hipStream_t stream) {
    (void)in_sizes; (void)n_in; (void)out_size; (void)ws_size;
    const float* behavior = (const float*)d_in[0];   // [B, L, D]
    const float* W        = (const float*)d_in[1];   // [D, D]
    const float* b_init   = (const float*)d_in[2];   // [B, K, L]
    const int*   mask     = (const int*)d_in[3];     // [B, L]
    float* out      = (float*)d_out;                 // [B, K, D]
    _Float16* uhat  = (_Float16*)d_ws;               // [B, L, D] fp16 scratch

    hipFuncSetAttribute((const void*)routing3,
                        hipFuncAttributeMaxDynamicSharedMemorySize, LDS_TOTAL);

    dim3 ggrid(2, 3200);
    uhat_gemm_f16<<<ggrid, 256, 0, stream>>>(behavior, W, uhat);
    routing3<<<2048, 1024, LDS_TOTAL, stream>>>(uhat, b_init, mask, out);
}

// Round 5
// 264.304 us; speedup vs baseline: 6.1721x; 1.5404x over previous
//
#include <hip/hip_runtime.h>
#include <hip/hip_bf16.h>

#define B_ 2048
#define L_ 200
#define D_ 256
#define K_ 8

typedef __attribute__((ext_vector_type(8))) _Float16 half8;
typedef __attribute__((ext_vector_type(4))) _Float16 half4v;
typedef __attribute__((ext_vector_type(4))) float f32x4;

// f16-element strides, chosen for bank spread (checked mod-32 in dwords)
#define LTP 232   // ut_T row stride (cols=l; data 0..199, zeros 200..231)
#define WP  232   // wH/wL row stride
#define CP  264   // cH/cL/Us/Xs row stride

// LDS offsets (bytes), all 16B-aligned
#define OFF_UTT  0                       // ut_T [256][232] f16 = 118784
#define OFF_WH   118784                  // wH   [16][232]  f16 = 7424
#define OFF_WL   126208                  // wL   [16][232]  f16 = 7424
#define OFF_CH   133632                  // cH   [16][264]  f16 = 8448  (overlay: Us)
#define OFF_CL   142080                  // cL   [16][264]  f16 = 8448  (overlay: Xs)
#define OFF_LB   150528                  // lb   [8][200]   f32 = 6400
#define OFF_RED  156928                  // red2 [16][8]    f32 = 512
#define OFF_SC   157440                  // scS  [8]        f32 = 32
#define LDS_TOTAL 157472                 // < 163840

// ------------------------------------------------------------------
// Kernel 0: W fp32 -> fp16 (65536 elems)
// ------------------------------------------------------------------
__global__ __launch_bounds__(256) void w_to_f16(const float* __restrict__ W,
                                                _Float16* __restrict__ Wh) {
    const int idx = (blockIdx.x * 256 + threadIdx.x) * 4;
    const float4 v = *(const float4*)(W + idx);
    half4v h = { (_Float16)v.x, (_Float16)v.y, (_Float16)v.z, (_Float16)v.w };
    *(half4v*)(Wh + idx) = h;
}

// ------------------------------------------------------------------
// Fused kernel: one block (1024 thr, 16 waves) per batch.
// Prologue: u_hat = X@W^T via MFMA, tile-wise; builds ut_T (LDS) and
// per-wave hoisted u A-frags (regs). Main: 3 routing iters, z-pass and
// b-update both MFMA; w and c in hi/lo fp16 splits (~fp32 accuracy).
// ------------------------------------------------------------------
__global__ __launch_bounds__(1024) void fused_mie(
        const float* __restrict__ X, const float* __restrict__ b_init,
        const int* __restrict__ mask, const _Float16* __restrict__ Wh,
        float* __restrict__ out) {
    extern __shared__ char dyn[];
    _Float16* utT = (_Float16*)(dyn + OFF_UTT);
    _Float16* wHs = (_Float16*)(dyn + OFF_WH);
    _Float16* wLs = (_Float16*)(dyn + OFF_WL);
    _Float16* cHs = (_Float16*)(dyn + OFF_CH);
    _Float16* cLs = (_Float16*)(dyn + OFF_CL);
    _Float16* Us  = (_Float16*)(dyn + OFF_CH);   // prologue overlay
    _Float16* Xs  = (_Float16*)(dyn + OFF_CL);   // prologue overlay
    float* lb   = (float*)(dyn + OFF_LB);
    float* red2 = (float*)(dyn + OFF_RED);
    float* scS  = (float*)(dyn + OFF_SC);

    const int b = blockIdx.x;
    const int t = threadIdx.x;
    const int w = t >> 6, lane = t & 63;
    const int fr = lane & 15, hi = lane >> 4;

    // ---------- one-time init ----------
    {   // zero ut_T padding cols 200..231 (MFMA K-padding; avoid NaN*0)
        const int row = t >> 2, part = t & 3;
        *(int4*)&utT[row * LTP + 200 + 8 * part] = make_int4(0, 0, 0, 0);
    }
    // zero wH/wL fully (rows k>=8 and cols l>=200 stay zero forever)
    if (t < 928) *(int4*)(dyn + OFF_WH + 16 * t) = make_int4(0, 0, 0, 0);
    // init logits with mask
    for (int idx = t; idx < K_ * L_; idx += 1024) {
        const int k = idx / L_, l = idx - k * L_;
        lb[idx] = (mask[b * L_ + l] == 0) ? -1e9f
                                          : b_init[(size_t)b * (K_ * L_) + idx];
    }

    // hoisted W B-frags: wave w owns u_hat cols e = 16w..16w+15
    half8 bw[8];
    {
        const _Float16* wr = Wh + (size_t)(16 * w + fr) * 256;
#pragma unroll
        for (int d0 = 0; d0 < 8; ++d0)
            bw[d0] = *(const half8*)(wr + 32 * d0 + 8 * hi);
    }

    // stage X tile 0 (rows 0..15)
    const float* Xb = X + (size_t)b * L_ * D_;
    const int sc4 = lane * 4;        // 0..252
    {
        const float4 v = *(const float4*)(Xb + w * 256 + sc4);
        half4v h = { (_Float16)v.x, (_Float16)v.y, (_Float16)v.z, (_Float16)v.w };
        *(half4v*)&Xs[w * CP + sc4] = h;
    }
    __syncthreads();

    // ---------- prologue: 13 l-tiles of 16 ----------
    half8 au[8];   // b-update A-frags (wave w <- l-tile w); waves 13..15 unused
    for (int lt = 0; lt < 13; ++lt) {
        // GEMM: u-tile[16 l][16 e] for this wave's e-range
        f32x4 acc = {};
#pragma unroll
        for (int d0 = 0; d0 < 8; ++d0) {
            const half8 a8 = *(const half8*)&Xs[fr * CP + 32 * d0 + 8 * hi];
            acc = __builtin_amdgcn_mfma_f32_16x16x32_f16(a8, bw[d0], acc, 0, 0, 0);
        }
        // prefetch next X tile into regs (hide HBM latency under syncs)
        float4 xv = make_float4(0.f, 0.f, 0.f, 0.f);
        if (lt < 12) {
            const int l = 16 * (lt + 1) + w;
            if (l < L_) xv = *(const float4*)(Xb + l * 256 + sc4);
        }
        // write u-tile to Us (row = l-in-tile, col = e)
#pragma unroll
        for (int j = 0; j < 4; ++j)
            Us[(4 * hi + j) * CP + 16 * w + fr] = (_Float16)acc[j];
        __syncthreads();
        // wave lt grabs its b-update A-frags (u rows 16lt+fr, d-contig)
        if (w == lt) {
#pragma unroll
            for (int d0 = 0; d0 < 8; ++d0)
                au[d0] = *(const half8*)&Us[fr * CP + 32 * d0 + 8 * hi];
        }
        {   // transpose Us -> ut_T: thread owns col c, rows r0..r0+3
            const int c = t & 255, r0 = (t >> 8) * 4;
            half4v p = { Us[(r0 + 0) * CP + c], Us[(r0 + 1) * CP + c],
                         Us[(r0 + 2) * CP + c], Us[(r0 + 3) * CP + c] };
            *(half4v*)&utT[c * LTP + 16 * lt + r0] = p;
        }
        // stage next X tile (Xs region disjoint from Us/utT; GEMM reads done)
        if (lt < 12) {
            half4v h = { (_Float16)xv.x, (_Float16)xv.y, (_Float16)xv.z, (_Float16)xv.w };
            *(half4v*)&Xs[w * CP + sc4] = h;
        }
        __syncthreads();
    }

    // ---------- routing iterations ----------
    for (int iter = 0; iter < 3; ++iter) {
        // A. softmax over l (waves 0..7; wave = capsule k); hi/lo fp16 w
        if (t < 512) {
            const int k = t >> 6, ln = t & 63;
            float v[4];
            float m = -1e30f;
#pragma unroll
            for (int i = 0; i < 4; ++i) {
                const int l = ln + 64 * i;
                v[i] = (l < L_) ? lb[k * L_ + l] : -1e30f;
                m = fmaxf(m, v[i]);
            }
#pragma unroll
            for (int off = 32; off >= 1; off >>= 1)
                m = fmaxf(m, __shfl_xor(m, off));
            float e[4], s = 0.f;
#pragma unroll
            for (int i = 0; i < 4; ++i) {
                const int l = ln + 64 * i;
                e[i] = (l < L_) ? __expf(v[i] - m) : 0.f;
                s += e[i];
            }
#pragma unroll
            for (int off = 32; off >= 1; off >>= 1)
                s += __shfl_xor(s, off);
            const float rinv = 1.0f / s;
#pragma unroll
            for (int i = 0; i < 4; ++i) {
                const int l = ln + 64 * i;
                if (l < L_) {
                    const float wv = e[i] * rinv;
                    const _Float16 h = (_Float16)wv;
                    wHs[k * WP + l] = h;
                    wLs[k * WP + l] = (_Float16)(wv - (float)h);
                }
            }
        }
        __syncthreads();

        // C. z-pass MFMA: wave w owns d-cols 16w..16w+15; K-dim = l (224)
        f32x4 zac = {};
#pragma unroll
        for (int ks = 0; ks < 7; ++ks) {
            const half8 bz = *(const half8*)&utT[(16 * w + fr) * LTP + 32 * ks + 8 * hi];
            const half8 ah = *(const half8*)&wHs[fr * WP + 32 * ks + 8 * hi];
            const half8 al = *(const half8*)&wLs[fr * WP + 32 * ks + 8 * hi];
            zac = __builtin_amdgcn_mfma_f32_16x16x32_f16(ah, bz, zac, 0, 0, 0);
            zac = __builtin_amdgcn_mfma_f32_16x16x32_f16(al, bz, zac, 0, 0, 0);
        }
        // lane holds z[k=4hi+j][d=16w+fr]; rows k>=8 are zero (wH rows zeroed)

        // D. squash norms: sum z^2 over fr within each 16-lane group
        float sq0 = zac[0] * zac[0], sq1 = zac[1] * zac[1];
        float sq2 = zac[2] * zac[2], sq3 = zac[3] * zac[3];
#pragma unroll
        for (int off = 1; off <= 8; off <<= 1) {
            sq0 += __shfl_xor(sq0, off);
            sq1 += __shfl_xor(sq1, off);
            sq2 += __shfl_xor(sq2, off);
            sq3 += __shfl_xor(sq3, off);
        }
        if (fr == 0 && hi < 2) {
            f32x4 sv = { sq0, sq1, sq2, sq3 };
            *(f32x4*)&red2[w * 8 + 4 * hi] = sv;
        }
        __syncthreads();
        if (t < 8) {
            float ns = 0.f;
#pragma unroll
            for (int ww = 0; ww < 16; ++ww) ns += red2[ww * 8 + t];
            scS[t] = ns / ((1.f + ns) * sqrtf(ns + 1e-8f));
        }
        __syncthreads();

        // E. emit c (hi/lo fp16) or final output
        if (iter == 2) {
            if (hi < 2) {
                const f32x4 sc = *(const f32x4*)&scS[4 * hi];
                float* op = out + (size_t)b * (K_ * D_) + (4 * hi) * D_ + 16 * w + fr;
#pragma unroll
                for (int j = 0; j < 4; ++j) op[j * D_] = sc[j] * zac[j];
            }
        } else {
            if (hi < 2) {
                const f32x4 sc = *(const f32x4*)&scS[4 * hi];
#pragma unroll
                for (int j = 0; j < 4; ++j) {
                    const float v = sc[j] * zac[j];
                    const _Float16 h = (_Float16)v;
                    cHs[(4 * hi + j) * CP + 16 * w + fr] = h;
                    cLs[(4 * hi + j) * CP + 16 * w + fr] = (_Float16)(v - (float)h);
                }
            }
            __syncthreads();

            // F. b-update MFMA: lb[k][l] += sum_d u[l,d]*c[k,d]
            if (w < 13) {
                f32x4 dac = {};
#pragma unroll
                for (int d0 = 0; d0 < 8; ++d0) {
                    const half8 bh = *(const half8*)&cHs[fr * CP + 32 * d0 + 8 * hi];
                    const half8 bl = *(const half8*)&cLs[fr * CP + 32 * d0 + 8 * hi];
                    dac = __builtin_amdgcn_mfma_f32_16x16x32_f16(au[d0], bh, dac, 0, 0, 0);
                    dac = __builtin_amdgcn_mfma_f32_16x16x32_f16(au[d0], bl, dac, 0, 0, 0);
                }
                // D[l-row][k-col]: col=fr (keep k<8), row l = 16w + 4hi + j
                if (fr < 8) {
#pragma unroll
                    for (int j = 0; j < 4; ++j) {
                        const int l = 16 * w + 4 * hi + j;
                        if (l < L_) lb[fr * L_ + l] += dac[j];
                    }
                }
            }
            __syncthreads();
        }
    }
}

// ==================================================================
extern "C" void kernel_launch(void* const* d_in, const int* in_sizes, int n_in,
                              void* d_out, int out_size, void* d_ws, size_t ws_size,
                              hipStream_t stream) {
    (void)in_sizes; (void)n_in; (void)out_size; (void)ws_size;
    const float* behavior = (const float*)d_in[0];   // [B, L, D]
    const float* W        = (const float*)d_in[1];   // [D, D]
    const float* b_init   = (const float*)d_in[2];   // [B, K, L]
    const int*   mask     = (const int*)d_in[3];     // [B, L]
    float* out      = (float*)d_out;                 // [B, K, D]
    _Float16* Wh    = (_Float16*)d_ws;               // [256,256] fp16 (128 KB)

    hipFuncSetAttribute((const void*)fused_mie,
                        hipFuncAttributeMaxDynamicSharedMemorySize, LDS_TOTAL);

    w_to_f16<<<64, 256, 0, stream>>>(W, Wh);
    fused_mie<<<B_, 1024, LDS_TOTAL, stream>>>(behavior, b_init, mask, Wh, out);
}